// Round 2
// baseline (15426.761 us; speedup 1.0000x reference)
//
#include <hip/hip_runtime.h>
#include <hip/hip_fp16.h>

typedef _Float16 f16;
typedef _Float16 f16x2 __attribute__((ext_vector_type(2)));
typedef _Float16 f16x4 __attribute__((ext_vector_type(4)));
typedef _Float16 f16x8 __attribute__((ext_vector_type(8)));
typedef float f32x4 __attribute__((ext_vector_type(4)));

// ---------------- cast fp32 -> f16 (x4 vectorized) ----------------
__global__ void cast_f32_f16(const float* __restrict__ in, f16* __restrict__ out, int n4) {
    int i = blockIdx.x * blockDim.x + threadIdx.x;
    if (i >= n4) return;
    float4 v = ((const float4*)in)[i];
    f16x4 o;
    o.x = (f16)v.x; o.y = (f16)v.y; o.z = (f16)v.z; o.w = (f16)v.w;
    ((f16x4*)out)[i] = o;
}

// ---------------- pack w_hh into [dir][k2][j][4 gates x f16x2] ----------------
// wq[(d*256 + k2)*512 + j] = uint4 whose 4 words are half2(w[g*512+j][2k2], w[g*512+j][2k2+1])
// for g = i,f,g,o. One uint4 = the 4-gate weights for h-index j at k-pair k2.
__global__ void pack_whh(const float* __restrict__ wf, const float* __restrict__ wb,
                         uint4* __restrict__ wq) {
    int tid = blockIdx.x * blockDim.x + threadIdx.x;   // 0 .. 2*256*512-1
    int j  = tid & 511;
    int k2 = (tid >> 9) & 255;
    int d  = tid >> 17;
    const float* w = d ? wb : wf;
    uint4 o;
    uint* po = (uint*)&o;
#pragma unroll
    for (int g = 0; g < 4; ++g) {
        float a  = w[(size_t)(g * 512 + j) * 512 + 2 * k2];
        float bv = w[(size_t)(g * 512 + j) * 512 + 2 * k2 + 1];
        f16x2 p; p.x = (f16)a; p.y = (f16)bv;
        po[g] = __builtin_bit_cast(uint, p);
    }
    wq[tid] = o;
}

// ---------------- input projection GEMM (f16 MFMA, fp32 accum) ----------------
// C[m][n] = sum_k A[m][k] * W[n][k] + bias[n];  M=16384, N=4096, K in {512,1024}
// 128x128 tile, BK=64, 4 waves (2x2 of 64x64), mfma_f32_16x16x32_f16.
__global__ __launch_bounds__(256)
void gemm_proj(const f16* __restrict__ A, const f16* __restrict__ W,
               const float* __restrict__ bias_f, const float* __restrict__ bias_b,
               f16* __restrict__ C, int K) {
    __shared__ f16 As[128 * 64];
    __shared__ f16 Bs[128 * 64];
    const int m0 = blockIdx.x * 128;
    const int n0 = blockIdx.y * 128;
    const int tid = threadIdx.x;
    const int lane = tid & 63;
    const int wave = tid >> 6;
    const int wm = wave >> 1, wn = wave & 1;
    const int r_in = tid >> 3;            // 0..31
    const int cb   = (tid & 7) * 16;      // byte col within 128B row
    f32x4 acc[4][4] = {};

    for (int k0 = 0; k0 < K; k0 += 64) {
#pragma unroll
        for (int c = 0; c < 4; ++c) {
            int row = c * 32 + r_in;
            *(uint4*)((char*)As + c * 4096 + tid * 16) =
                *(const uint4*)((const char*)A + ((size_t)(m0 + row) * K + k0) * 2 + cb);
            *(uint4*)((char*)Bs + c * 4096 + tid * 16) =
                *(const uint4*)((const char*)W + ((size_t)(n0 + row) * K + k0) * 2 + cb);
        }
        __syncthreads();
#pragma unroll
        for (int ks = 0; ks < 2; ++ks) {
            f16x8 af[4], bf[4];
            const int ko = ks * 64 + ((lane >> 4) * 16);   // byte offset in row
#pragma unroll
            for (int i2 = 0; i2 < 4; ++i2) {
                af[i2] = *(const f16x8*)((const char*)As + (wm * 64 + i2 * 16 + (lane & 15)) * 128 + ko);
                bf[i2] = *(const f16x8*)((const char*)Bs + (wn * 64 + i2 * 16 + (lane & 15)) * 128 + ko);
            }
#pragma unroll
            for (int i2 = 0; i2 < 4; ++i2)
#pragma unroll
                for (int j2 = 0; j2 < 4; ++j2)
                    acc[i2][j2] = __builtin_amdgcn_mfma_f32_16x16x32_f16(af[i2], bf[j2], acc[i2][j2], 0, 0, 0);
        }
        __syncthreads();
    }
    // C/D layout: col = lane&15, row = (lane>>4)*4 + r
#pragma unroll
    for (int i2 = 0; i2 < 4; ++i2) {
        const int row = m0 + wm * 64 + i2 * 16 + ((lane >> 4) << 2);
#pragma unroll
        for (int j2 = 0; j2 < 4; ++j2) {
            const int col = n0 + wn * 64 + j2 * 16 + (lane & 15);
            const float bs = (col < 2048) ? bias_f[col] : bias_b[col - 2048];
#pragma unroll
            for (int r = 0; r < 4; ++r)
                C[(size_t)(row + r) * 4096 + col] = (f16)(acc[i2][j2][r] + bs);
        }
    }
}

// ---------------- LSTM recurrence ----------------
// One WG per (batch, dir). 512 threads; thread j owns h-index j (all 4 gates).
// h state (fp32) in LDS, broadcast-read; weights streamed f16-packed from L2.
__device__ __forceinline__ float sigm(float x) { return 1.f / (1.f + __expf(-x)); }
__device__ __forceinline__ float tanhfast(float x) { return 1.f - 2.f / (__expf(2.f * x) + 1.f); }

template <typename OutT>
__global__ __launch_bounds__(512)
void lstm_rec(const f16* __restrict__ xp,      // (32*512, 4096) f16; n = d*2048 + gate*512 + j
              const uint4* __restrict__ wq,    // [2][256][512] uint4
              OutT* __restrict__ out) {        // (32*512, 1024); n = d*512 + j
    __shared__ float h_lds[512];
    const int xcd = blockIdx.x & 7;
    const int r   = blockIdx.x >> 3;
    const int d   = (xcd >= 4) ? 1 : 0;       // dir-per-XCD-half (L2 locality heuristic)
    const int b   = r * 4 + (xcd & 3);
    const int j   = threadIdx.x;
    const uint4* __restrict__ wptr = wq + ((size_t)d << 17) + j;
    float c = 0.f;
    h_lds[j] = 0.f;
    __syncthreads();

    for (int step = 0; step < 512; ++step) {
        const int t = d ? (511 - step) : step;
        const f16* xr = xp + ((size_t)(b * 512 + t) << 12) + (d << 11) + j;
        float gi = (float)xr[0];
        float gf = (float)xr[512];
        float gg = (float)xr[1024];
        float go = (float)xr[1536];

        uint4 wa  = wptr[0];
        uint4 wb2 = wptr[512];
#pragma unroll 2
        for (int k2 = 0; k2 < 256; k2 += 2) {
            const int kn = (k2 + 2) & 255;             // wraps at end (harmless valid read)
            uint4 na = wptr[(size_t)kn * 512];
            uint4 nb = wptr[(size_t)(kn + 1) * 512];
            const float4 h4 = *(const float4*)&h_lds[k2 * 2];
            f16x2 p;
            p = __builtin_bit_cast(f16x2, wa.x);  gi = fmaf((float)p.x, h4.x, gi); gi = fmaf((float)p.y, h4.y, gi);
            p = __builtin_bit_cast(f16x2, wa.y);  gf = fmaf((float)p.x, h4.x, gf); gf = fmaf((float)p.y, h4.y, gf);
            p = __builtin_bit_cast(f16x2, wa.z);  gg = fmaf((float)p.x, h4.x, gg); gg = fmaf((float)p.y, h4.y, gg);
            p = __builtin_bit_cast(f16x2, wa.w);  go = fmaf((float)p.x, h4.x, go); go = fmaf((float)p.y, h4.y, go);
            p = __builtin_bit_cast(f16x2, wb2.x); gi = fmaf((float)p.x, h4.z, gi); gi = fmaf((float)p.y, h4.w, gi);
            p = __builtin_bit_cast(f16x2, wb2.y); gf = fmaf((float)p.x, h4.z, gf); gf = fmaf((float)p.y, h4.w, gf);
            p = __builtin_bit_cast(f16x2, wb2.z); gg = fmaf((float)p.x, h4.z, gg); gg = fmaf((float)p.y, h4.w, gg);
            p = __builtin_bit_cast(f16x2, wb2.w); go = fmaf((float)p.x, h4.z, go); go = fmaf((float)p.y, h4.w, go);
            wa = na; wb2 = nb;
        }

        const float iv = sigm(gi), fv = sigm(gf), ov = sigm(go);
        const float gv = tanhfast(gg);
        c = fv * c + iv * gv;
        const float hn = ov * tanhfast(c);

        __syncthreads();                 // everyone done reading old h
        h_lds[j] = hn;
        out[((size_t)(b * 512 + t) << 10) + (d << 9) + j] = (OutT)hn;
        __syncthreads();                 // new h visible
    }
}

// ---------------- launch ----------------
extern "C" void kernel_launch(void* const* d_in, const int* in_sizes, int n_in,
                              void* d_out, int out_size, void* d_ws, size_t ws_size,
                              hipStream_t stream) {
    const float* x      = (const float*)d_in[0];
    const float* wih_f0 = (const float*)d_in[1];
    const float* bih_f0 = (const float*)d_in[2];
    const float* whh_f0 = (const float*)d_in[3];
    const float* wih_b0 = (const float*)d_in[4];
    const float* bih_b0 = (const float*)d_in[5];
    const float* whh_b0 = (const float*)d_in[6];
    const float* wih_f1 = (const float*)d_in[7];
    const float* bih_f1 = (const float*)d_in[8];
    const float* whh_f1 = (const float*)d_in[9];
    const float* wih_b1 = (const float*)d_in[10];
    const float* bih_b1 = (const float*)d_in[11];
    const float* whh_b1 = (const float*)d_in[12];

    char* ws = (char*)d_ws;
    f16*   xh   = (f16*)(ws);                       //  16,777,216 B
    f16*   wih0 = (f16*)(ws + 16777216);            //   4,194,304 B
    f16*   wih1 = (f16*)(ws + 20971520);            //   8,388,608 B
    uint4* wq0  = (uint4*)(ws + 29360128);          //   4,194,304 B
    uint4* wq1  = (uint4*)(ws + 33554432);          //   4,194,304 B
    f16*   xp   = (f16*)(ws + 37748736);            // 134,217,728 B (ends ~172MB)
    f16*   interh = (f16*)d_out;                    // inter-layer scratch inside d_out (33.5MB of 67MB)

    auto cast = [&](const float* in, f16* o, int n) {
        int n4 = n / 4;
        cast_f32_f16<<<(n4 + 255) / 256, 256, 0, stream>>>(in, o, n4);
    };
    cast(x, xh, 8388608);
    cast(wih_f0, wih0, 1048576);
    cast(wih_b0, wih0 + 1048576, 1048576);
    cast(wih_f1, wih1, 2097152);
    cast(wih_b1, wih1 + 2097152, 2097152);
    pack_whh<<<1024, 256, 0, stream>>>(whh_f0, whh_b0, wq0);
    pack_whh<<<1024, 256, 0, stream>>>(whh_f1, whh_b1, wq1);

    // layer 0
    gemm_proj<<<dim3(128, 32), 256, 0, stream>>>(xh, wih0, bih_f0, bih_b0, xp, 512);
    lstm_rec<f16><<<64, 512, 0, stream>>>(xp, wq0, interh);
    // layer 1
    gemm_proj<<<dim3(128, 32), 256, 0, stream>>>(interh, wih1, bih_f1, bih_b1, xp, 1024);
    lstm_rec<float><<<64, 512, 0, stream>>>(xp, wq1, (float*)d_out);
}

// Round 3
// 15123.711 us; speedup vs baseline: 1.0200x; 1.0200x over previous
//
#include <hip/hip_runtime.h>
#include <hip/hip_fp16.h>

typedef _Float16 f16;
typedef _Float16 f16x2 __attribute__((ext_vector_type(2)));
typedef _Float16 f16x4 __attribute__((ext_vector_type(4)));
typedef _Float16 f16x8 __attribute__((ext_vector_type(8)));
typedef float f32x4 __attribute__((ext_vector_type(4)));

// ---------------- cast fp32 -> f16 (x4 vectorized) ----------------
__global__ void cast_f32_f16(const float* __restrict__ in, f16* __restrict__ out, int n4) {
    int i = blockIdx.x * blockDim.x + threadIdx.x;
    if (i >= n4) return;
    float4 v = ((const float4*)in)[i];
    f16x4 o;
    o.x = (f16)v.x; o.y = (f16)v.y; o.z = (f16)v.z; o.w = (f16)v.w;
    ((f16x4*)out)[i] = o;
}

// ---------------- pack w_hh for register-resident layout ----------------
// wr[d][slice(16)][tid(512)][i(64)] : uint = f16x2 = w[g*512+j][k], w[..][k+1]
// where tid = (g*32+jj)*4 + kq, j = slice*32+jj, k = kq*128 + i*2.
__global__ void pack_whh_reg(const float* __restrict__ wf, const float* __restrict__ wb,
                             uint* __restrict__ wr) {
    int gidx = blockIdx.x * blockDim.x + threadIdx.x;   // [0, 2*16*512*64)
    if (gidx >= (2 * 16 * 512 * 64)) return;
    int i     = gidx & 63;
    int tid   = (gidx >> 6) & 511;
    int slice = (gidx >> 15) & 15;
    int d     = gidx >> 19;
    int kq = tid & 3, row = tid >> 2, g = row >> 5, jj = row & 31;
    int j = slice * 32 + jj;
    int k = kq * 128 + i * 2;
    const float* w = d ? wb : wf;
    const float* base = w + (size_t)(g * 512 + j) * 512 + k;
    f16x2 p; p.x = (f16)base[0]; p.y = (f16)base[1];
    wr[gidx] = __builtin_bit_cast(uint, p);
}

// ---------------- input projection GEMM (f16 MFMA, fp32 accum) ----------------
__global__ __launch_bounds__(256)
void gemm_proj(const f16* __restrict__ A, const f16* __restrict__ W,
               const float* __restrict__ bias_f, const float* __restrict__ bias_b,
               f16* __restrict__ C, int K) {
    __shared__ f16 As[128 * 64];
    __shared__ f16 Bs[128 * 64];
    const int m0 = blockIdx.x * 128;
    const int n0 = blockIdx.y * 128;
    const int tid = threadIdx.x;
    const int lane = tid & 63;
    const int wave = tid >> 6;
    const int wm = wave >> 1, wn = wave & 1;
    const int r_in = tid >> 3;
    const int cb   = (tid & 7) * 16;
    f32x4 acc[4][4] = {};

    for (int k0 = 0; k0 < K; k0 += 64) {
#pragma unroll
        for (int c = 0; c < 4; ++c) {
            int row = c * 32 + r_in;
            *(uint4*)((char*)As + c * 4096 + tid * 16) =
                *(const uint4*)((const char*)A + ((size_t)(m0 + row) * K + k0) * 2 + cb);
            *(uint4*)((char*)Bs + c * 4096 + tid * 16) =
                *(const uint4*)((const char*)W + ((size_t)(n0 + row) * K + k0) * 2 + cb);
        }
        __syncthreads();
#pragma unroll
        for (int ks = 0; ks < 2; ++ks) {
            f16x8 af[4], bf[4];
            const int ko = ks * 64 + ((lane >> 4) * 16);
#pragma unroll
            for (int i2 = 0; i2 < 4; ++i2) {
                af[i2] = *(const f16x8*)((const char*)As + (wm * 64 + i2 * 16 + (lane & 15)) * 128 + ko);
                bf[i2] = *(const f16x8*)((const char*)Bs + (wn * 64 + i2 * 16 + (lane & 15)) * 128 + ko);
            }
#pragma unroll
            for (int i2 = 0; i2 < 4; ++i2)
#pragma unroll
                for (int j2 = 0; j2 < 4; ++j2)
                    acc[i2][j2] = __builtin_amdgcn_mfma_f32_16x16x32_f16(af[i2], bf[j2], acc[i2][j2], 0, 0, 0);
        }
        __syncthreads();
    }
#pragma unroll
    for (int i2 = 0; i2 < 4; ++i2) {
        const int row = m0 + wm * 64 + i2 * 16 + ((lane >> 4) << 2);
#pragma unroll
        for (int j2 = 0; j2 < 4; ++j2) {
            const int col = n0 + wn * 64 + j2 * 16 + (lane & 15);
            const float bs = (col < 2048) ? bias_f[col] : bias_b[col - 2048];
#pragma unroll
            for (int r = 0; r < 4; ++r)
                C[(size_t)(row + r) * 4096 + col] = (f16)(acc[i2][j2][r] + bs);
        }
    }
}

// ---------------- LSTM recurrence: register-resident weights + cross-WG h-exchange ----
__device__ __forceinline__ float sigm(float x) { return 1.f / (1.f + __expf(-x)); }
__device__ __forceinline__ float tanhfast(float x) { return 1.f - 2.f / (__expf(2.f * x) + 1.f); }

__device__ __forceinline__ float fdot2f(uint w2, uint h2, float acc) {
#if __has_builtin(__builtin_amdgcn_fdot2)
    return __builtin_amdgcn_fdot2(__builtin_bit_cast(f16x2, w2),
                                  __builtin_bit_cast(f16x2, h2), acc, false);
#else
    f16x2 a = __builtin_bit_cast(f16x2, w2), b = __builtin_bit_cast(f16x2, h2);
    return fmaf((float)a.y, (float)b.y, fmaf((float)a.x, (float)b.x, acc));
#endif
}

// Grid = 256 WGs x 512 threads (exactly 1 WG/CU, all resident -> spin-safe).
// WG = (dir d, batch-group bg of 4, j-slice of 32). Group = 16 slice-WGs of (d,bg).
// Thread tid = (g*32+jj)*4 + kq: owns w_hh[g*512 + slice*32+jj][kq*128 .. +128] in 64 VGPRs.
template <typename OutT>
__global__ __launch_bounds__(512)
void lstm_rec(const f16* __restrict__ xp,      // (32*512, 4096): n = d*2048 + g*512 + j
              const uint* __restrict__ wr,     // [2][16][512][64]
              f16* __restrict__ hx,            // [2 par][2 d][8 bg][4 b][512]
              unsigned* __restrict__ cnt,      // [16] zeroed before launch
              OutT* __restrict__ out) {        // (32*512, 1024): n = d*512 + j
    __shared__ f16  h_lds[4][512];
    __shared__ float gbuf[128][4];
    const int tid = threadIdx.x;
    const int bid = blockIdx.x;
    const int xcd   = bid & 7;
    const int idx   = bid >> 3;                 // 0..31
    const int gid   = xcd * 2 + (idx >> 4);     // 0..15 (group on one XCD if round-robin)
    const int slice = idx & 15;
    const int d  = gid >> 3;
    const int bg = gid & 7;
    const int kq  = tid & 3;
    const int ab  = tid >> 5, ajj = tid & 31;   // activation role (tid<128)

    // weights -> registers (once)
    uint w[64];
    {
        const uint4* wp = (const uint4*)(wr + (((size_t)d * 16 + slice) * 512 + tid) * 64);
#pragma unroll
        for (int i = 0; i < 16; ++i) {
            uint4 v = wp[i];
            w[i * 4 + 0] = v.x; w[i * 4 + 1] = v.y; w[i * 4 + 2] = v.z; w[i * 4 + 3] = v.w;
        }
    }
    ((uint2*)h_lds)[tid] = make_uint2(0u, 0u);   // h0 = 0
    float cc = 0.f;                               // c state (activation lanes)
    unsigned* cg = cnt + gid;
    unsigned target = 0;
    __syncthreads();

    for (int step = 0; step < 512; ++step) {
        const int t = d ? (511 - step) : step;

        // xp prefetch for activation lanes (latency hidden under dot)
        float xg0 = 0.f, xg1 = 0.f, xg2 = 0.f, xg3 = 0.f;
        if (tid < 128) {
            const f16* xr = xp + ((size_t)((bg * 4 + ab) * 512 + t) << 12) + (d << 11)
                            + slice * 32 + ajj;
            xg0 = (float)xr[0];
            xg1 = (float)xr[512];
            xg2 = (float)xr[1024];
            xg3 = (float)xr[1536];
        }

        // dot: gate partial over this thread's k-quarter, 4 batches
        float acc[4];
#pragma unroll
        for (int b = 0; b < 4; ++b) {
            float a = 0.f;
            const uint4* hp = (const uint4*)&h_lds[b][kq << 7];
#pragma unroll
            for (int i = 0; i < 16; ++i) {
                uint4 hv = hp[i];
                a = fdot2f(w[i * 4 + 0], hv.x, a);
                a = fdot2f(w[i * 4 + 1], hv.y, a);
                a = fdot2f(w[i * 4 + 2], hv.z, a);
                a = fdot2f(w[i * 4 + 3], hv.w, a);
            }
            acc[b] = a;
        }
        // reduce over kq (lanes tid = row*4 + kq, same wave)
#pragma unroll
        for (int b = 0; b < 4; ++b) {
            acc[b] += __shfl_xor(acc[b], 1);
            acc[b] += __shfl_xor(acc[b], 2);
        }
        if (kq == 0)
            *(float4*)&gbuf[tid >> 2][0] = make_float4(acc[0], acc[1], acc[2], acc[3]);
        __syncthreads();

        const int par = step & 1;
        if (tid < 128) {
            float gi = gbuf[ajj][ab]      + xg0;
            float gf = gbuf[32 + ajj][ab] + xg1;
            float gg = gbuf[64 + ajj][ab] + xg2;
            float go = gbuf[96 + ajj][ab] + xg3;
            float iv = sigm(gi), fv = sigm(gf), ov = sigm(go), gv = tanhfast(gg);
            cc = fv * cc + iv * gv;
            float hn = ov * tanhfast(cc);
            hx[((((par * 2 + d) * 8 + bg) * 4 + ab) << 9) + slice * 32 + ajj] = (f16)hn;
            out[((size_t)((bg * 4 + ab) * 512 + t) << 10) + (d << 9) + slice * 32 + ajj] = (OutT)hn;
        }
        __syncthreads();   // drains hx/out stores (vmcnt 0 before barrier)

        target += 16;
        if (tid == 0) {
            __hip_atomic_fetch_add(cg, 1u, __ATOMIC_ACQ_REL, __HIP_MEMORY_SCOPE_AGENT);
            int guard = 0;
            while (__hip_atomic_load(cg, __ATOMIC_ACQUIRE, __HIP_MEMORY_SCOPE_AGENT) < target
                   && guard < (1 << 22)) {
                __builtin_amdgcn_s_sleep(2);
                ++guard;
            }
        }
        __syncthreads();

        // read full group h (4 b x 512) -> LDS for next step
        {
            const int hb = tid >> 7;        // 0..3
            const int k4 = tid & 127;       // 4 f16 per thread
            const unsigned long long hv8 = __hip_atomic_load(
                (const unsigned long long*)(hx + ((((par * 2 + d) * 8 + bg) * 4 + hb) << 9) + k4 * 4),
                __ATOMIC_RELAXED, __HIP_MEMORY_SCOPE_AGENT);
            *(unsigned long long*)&h_lds[hb][k4 * 4] = hv8;
        }
        __syncthreads();
    }
}

// ---------------- launch ----------------
extern "C" void kernel_launch(void* const* d_in, const int* in_sizes, int n_in,
                              void* d_out, int out_size, void* d_ws, size_t ws_size,
                              hipStream_t stream) {
    const float* x      = (const float*)d_in[0];
    const float* wih_f0 = (const float*)d_in[1];
    const float* bih_f0 = (const float*)d_in[2];
    const float* whh_f0 = (const float*)d_in[3];
    const float* wih_b0 = (const float*)d_in[4];
    const float* bih_b0 = (const float*)d_in[5];
    const float* whh_b0 = (const float*)d_in[6];
    const float* wih_f1 = (const float*)d_in[7];
    const float* bih_f1 = (const float*)d_in[8];
    const float* whh_f1 = (const float*)d_in[9];
    const float* wih_b1 = (const float*)d_in[10];
    const float* bih_b1 = (const float*)d_in[11];
    const float* whh_b1 = (const float*)d_in[12];

    char* ws = (char*)d_ws;
    f16*   xh   = (f16*)(ws);                       // 16 MB (dead after gemm L0)
    f16*   hx   = (f16*)(ws);                       // 128 KB, reuses dead xh region
    unsigned* cnt = (unsigned*)(ws + 131072);       // 64 B, also inside xh region
    f16*   wih0 = (f16*)(ws + 16777216);            // 4 MB
    f16*   wih1 = (f16*)(ws + 20971520);            // 8 MB
    uint*  wr0  = (uint*)(ws + 29360128);           // 4 MB
    uint*  wr1  = (uint*)(ws + 33554432);           // 4 MB
    f16*   xp   = (f16*)(ws + 37748736);            // 128 MB
    f16*   interh = (f16*)d_out;                    // inter-layer buffer inside d_out

    auto cast = [&](const float* in, f16* o, int n) {
        int n4 = n / 4;
        cast_f32_f16<<<(n4 + 255) / 256, 256, 0, stream>>>(in, o, n4);
    };
    cast(x, xh, 8388608);
    cast(wih_f0, wih0, 1048576);
    cast(wih_b0, wih0 + 1048576, 1048576);
    cast(wih_f1, wih1, 2097152);
    cast(wih_b1, wih1 + 2097152, 2097152);
    pack_whh_reg<<<4096, 256, 0, stream>>>(whh_f0, whh_b0, wr0);
    pack_whh_reg<<<4096, 256, 0, stream>>>(whh_f1, whh_b1, wr1);

    // layer 0
    gemm_proj<<<dim3(128, 32), 256, 0, stream>>>(xh, wih0, bih_f0, bih_b0, xp, 512);
    hipMemsetAsync(cnt, 0, 64, stream);
    lstm_rec<f16><<<256, 512, 0, stream>>>(xp, wr0, hx, cnt, interh);
    // layer 1
    gemm_proj<<<dim3(128, 32), 256, 0, stream>>>(interh, wih1, bih_f1, bih_b1, xp, 1024);
    hipMemsetAsync(cnt, 0, 64, stream);
    lstm_rec<float><<<256, 512, 0, stream>>>(xp, wr1, hx, cnt, (float*)d_out);
}

// Round 4
// 4498.765 us; speedup vs baseline: 3.4291x; 3.3617x over previous
//
#include <hip/hip_runtime.h>
#include <hip/hip_fp16.h>

typedef _Float16 f16;
typedef _Float16 f16x2 __attribute__((ext_vector_type(2)));
typedef _Float16 f16x4 __attribute__((ext_vector_type(4)));
typedef _Float16 f16x8 __attribute__((ext_vector_type(8)));
typedef float f32x4 __attribute__((ext_vector_type(4)));

// ---------------- cast fp32 -> f16 (x4 vectorized) ----------------
__global__ void cast_f32_f16(const float* __restrict__ in, f16* __restrict__ out, int n4) {
    int i = blockIdx.x * blockDim.x + threadIdx.x;
    if (i >= n4) return;
    float4 v = ((const float4*)in)[i];
    f16x4 o;
    o.x = (f16)v.x; o.y = (f16)v.y; o.z = (f16)v.z; o.w = (f16)v.w;
    ((f16x4*)out)[i] = o;
}

// ---------------- pack w_hh for register-resident layout (rotated chunk order) ----
// Thread tid = (g*32+jj)*4 + kq owns w[g*512 + slice*32+jj][kq*128 .. +128).
// Its 16-byte chunk r (r=0..15) holds logical k-subchunk s = (r + 2*kq) & 15,
// i.e. k = kq*128 + s*8 + u*2 for uint u=0..3. This matches the reader's
// bank-conflict-free rotated LDS walk.
__global__ void pack_whh_reg(const float* __restrict__ wf, const float* __restrict__ wb,
                             uint* __restrict__ wr) {
    int gidx = blockIdx.x * blockDim.x + threadIdx.x;   // [0, 2*16*512*64)
    if (gidx >= (2 * 16 * 512 * 64)) return;
    int i     = gidx & 63;          // uint index within thread (chunk r = i>>2, u = i&3)
    int tid   = (gidx >> 6) & 511;
    int slice = (gidx >> 15) & 15;
    int d     = gidx >> 19;
    int kq = tid & 3, row = tid >> 2, g = row >> 5, jj = row & 31;
    int r = i >> 2, u = i & 3;
    int s = (r + 2 * kq) & 15;
    int j = slice * 32 + jj;
    int k = kq * 128 + s * 8 + u * 2;
    const float* w = d ? wb : wf;
    const float* base = w + (size_t)(g * 512 + j) * 512 + k;
    f16x2 p; p.x = (f16)base[0]; p.y = (f16)base[1];
    wr[gidx] = __builtin_bit_cast(uint, p);
}

// ---------------- input projection GEMM (f16 MFMA, fp32 accum) ----------------
__global__ __launch_bounds__(256)
void gemm_proj(const f16* __restrict__ A, const f16* __restrict__ W,
               const float* __restrict__ bias_f, const float* __restrict__ bias_b,
               f16* __restrict__ C, int K) {
    __shared__ f16 As[128 * 64];
    __shared__ f16 Bs[128 * 64];
    const int m0 = blockIdx.x * 128;
    const int n0 = blockIdx.y * 128;
    const int tid = threadIdx.x;
    const int lane = tid & 63;
    const int wave = tid >> 6;
    const int wm = wave >> 1, wn = wave & 1;
    const int r_in = tid >> 3;
    const int cb   = (tid & 7) * 16;
    f32x4 acc[4][4] = {};

    for (int k0 = 0; k0 < K; k0 += 64) {
#pragma unroll
        for (int c = 0; c < 4; ++c) {
            int row = c * 32 + r_in;
            *(uint4*)((char*)As + c * 4096 + tid * 16) =
                *(const uint4*)((const char*)A + ((size_t)(m0 + row) * K + k0) * 2 + cb);
            *(uint4*)((char*)Bs + c * 4096 + tid * 16) =
                *(const uint4*)((const char*)W + ((size_t)(n0 + row) * K + k0) * 2 + cb);
        }
        __syncthreads();
#pragma unroll
        for (int ks = 0; ks < 2; ++ks) {
            f16x8 af[4], bf[4];
            const int ko = ks * 64 + ((lane >> 4) * 16);
#pragma unroll
            for (int i2 = 0; i2 < 4; ++i2) {
                af[i2] = *(const f16x8*)((const char*)As + (wm * 64 + i2 * 16 + (lane & 15)) * 128 + ko);
                bf[i2] = *(const f16x8*)((const char*)Bs + (wn * 64 + i2 * 16 + (lane & 15)) * 128 + ko);
            }
#pragma unroll
            for (int i2 = 0; i2 < 4; ++i2)
#pragma unroll
                for (int j2 = 0; j2 < 4; ++j2)
                    acc[i2][j2] = __builtin_amdgcn_mfma_f32_16x16x32_f16(af[i2], bf[j2], acc[i2][j2], 0, 0, 0);
        }
        __syncthreads();
    }
#pragma unroll
    for (int i2 = 0; i2 < 4; ++i2) {
        const int row = m0 + wm * 64 + i2 * 16 + ((lane >> 4) << 2);
#pragma unroll
        for (int j2 = 0; j2 < 4; ++j2) {
            const int col = n0 + wn * 64 + j2 * 16 + (lane & 15);
            const float bs = (col < 2048) ? bias_f[col] : bias_b[col - 2048];
#pragma unroll
            for (int r = 0; r < 4; ++r)
                C[(size_t)(row + r) * 4096 + col] = (f16)(acc[i2][j2][r] + bs);
        }
    }
}

// ---------------- LSTM recurrence: reg-resident weights, relaxed L3 sync ----------
__device__ __forceinline__ float sigm(float x) { return 1.f / (1.f + __expf(-x)); }
__device__ __forceinline__ float tanhfast(float x) { return 1.f - 2.f / (__expf(2.f * x) + 1.f); }

__device__ __forceinline__ float fdot2f(uint w2, uint h2, float acc) {
#if __has_builtin(__builtin_amdgcn_fdot2)
    return __builtin_amdgcn_fdot2(__builtin_bit_cast(f16x2, w2),
                                  __builtin_bit_cast(f16x2, h2), acc, false);
#else
    f16x2 a = __builtin_bit_cast(f16x2, w2), b = __builtin_bit_cast(f16x2, h2);
    return fmaf((float)a.y, (float)b.y, fmaf((float)a.x, (float)b.x, acc));
#endif
}

// Grid = 256 WGs x 512 threads (1 WG/CU, all resident -> spin-safe).
// WG = (dir d, batch-group bg of 4, j-slice of 32). Group = 16 slice-WGs of (d,bg).
// Protocol: h published via RELAXED agent atomic u32 stores (sc1 -> L3, no L2
// inv/wb); __syncthreads drains vmcnt so stores are L3-acked before the relaxed
// fetch_add; pollers use relaxed loads. No acquire/release anywhere in the loop.
template <typename OutT>
__global__ __launch_bounds__(512)
void lstm_rec(const f16* __restrict__ xp,      // (32*512, 4096): n = d*2048 + g*512 + j
              const uint* __restrict__ wr,     // [2][16][512][64]
              uint* __restrict__ hx,           // [2 par][2 d][8 bg][4 b][256 u32]
              unsigned* __restrict__ cnt,      // [16] zeroed before launch
              OutT* __restrict__ out) {        // (32*512, 1024): n = d*512 + j
    __shared__ f16  h_lds[4][512];
    __shared__ float gbuf[128][4];
    const int tid = threadIdx.x;
    const int bid = blockIdx.x;
    const int xcd   = bid & 7;
    const int idx   = bid >> 3;                 // 0..31
    const int gid   = xcd * 2 + (idx >> 4);     // 0..15
    const int slice = idx & 15;
    const int d  = gid >> 3;
    const int bg = gid & 7;
    const int kq  = tid & 3;
    const int ab  = tid >> 5, ajj = tid & 31;   // activation role (tid<128)

    // weights -> registers (once); asm pin prevents re-materializing loads in-loop
    uint w[64];
    {
        const uint4* wp = (const uint4*)(wr + (((size_t)d * 16 + slice) * 512 + tid) * 64);
#pragma unroll
        for (int i = 0; i < 16; ++i) {
            uint4 v = wp[i];
            w[i * 4 + 0] = v.x; w[i * 4 + 1] = v.y; w[i * 4 + 2] = v.z; w[i * 4 + 3] = v.w;
        }
#pragma unroll
        for (int i = 0; i < 64; ++i) asm volatile("" : "+v"(w[i]));
    }
    ((uint2*)h_lds)[tid] = make_uint2(0u, 0u);   // h0 = 0
    float cc = 0.f;                               // c state (activation lanes)
    unsigned* cg = cnt + gid;
    unsigned target = 0;
    __syncthreads();

    for (int step = 0; step < 512; ++step) {
        const int t = d ? (511 - step) : step;

        // xp prefetch for activation lanes (latency hidden under dot)
        float xg0 = 0.f, xg1 = 0.f, xg2 = 0.f, xg3 = 0.f;
        if (tid < 128) {
            const f16* xr = xp + ((size_t)((bg * 4 + ab) * 512 + t) << 12) + (d << 11)
                            + slice * 32 + ajj;
            xg0 = (float)xr[0];
            xg1 = (float)xr[512];
            xg2 = (float)xr[1024];
            xg3 = (float)xr[1536];
        }

        // dot: gate partial over this thread's k-quarter, 4 batches.
        // Rotated chunk walk s=(r+2kq)&15 -> the 4 kq quarters hit different banks.
        float acc[4];
#pragma unroll
        for (int b = 0; b < 4; ++b) {
            float a = 0.f;
            const char* hb = (const char*)&h_lds[b][0] + (kq << 8);
#pragma unroll
            for (int r = 0; r < 16; ++r) {
                const int s = (r + (kq << 1)) & 15;
                uint4 hv = *(const uint4*)(hb + (s << 4));
                a = fdot2f(w[r * 4 + 0], hv.x, a);
                a = fdot2f(w[r * 4 + 1], hv.y, a);
                a = fdot2f(w[r * 4 + 2], hv.z, a);
                a = fdot2f(w[r * 4 + 3], hv.w, a);
            }
            acc[b] = a;
        }
#pragma unroll
        for (int b = 0; b < 4; ++b) {
            acc[b] += __shfl_xor(acc[b], 1);
            acc[b] += __shfl_xor(acc[b], 2);
        }
        if (kq == 0)
            *(float4*)&gbuf[tid >> 2][0] = make_float4(acc[0], acc[1], acc[2], acc[3]);
        __syncthreads();

        const int par = step & 1;
        if (tid < 128) {
            float gi = gbuf[ajj][ab]      + xg0;
            float gf = gbuf[32 + ajj][ab] + xg1;
            float gg = gbuf[64 + ajj][ab] + xg2;
            float go = gbuf[96 + ajj][ab] + xg3;
            float iv = sigm(gi), fv = sigm(gf), ov = sigm(go), gv = tanhfast(gg);
            cc = fv * cc + iv * gv;
            float hn = ov * tanhfast(cc);
            // pair lanes -> one relaxed agent atomic u32 store per even lane (lands at L3)
            float ho = __shfl_xor(hn, 1);
            if ((tid & 1) == 0) {
                f16x2 pv; pv.x = (f16)hn; pv.y = (f16)ho;
                const int uidx = ((((par * 2 + d) * 8 + bg) * 4 + ab) << 8)
                                 + slice * 16 + (ajj >> 1);
                __hip_atomic_store(hx + uidx, __builtin_bit_cast(uint, pv),
                                   __ATOMIC_RELAXED, __HIP_MEMORY_SCOPE_AGENT);
            }
            out[((size_t)((bg * 4 + ab) * 512 + t) << 10) + (d << 9) + slice * 32 + ajj] = (OutT)hn;
        }
        __syncthreads();   // vmcnt(0) drain: h stores L3-acked before arrival signal

        target += 16;
        if (tid == 0) {
            __hip_atomic_fetch_add(cg, 1u, __ATOMIC_RELAXED, __HIP_MEMORY_SCOPE_AGENT);
            int guard = 0;
            while (__hip_atomic_load(cg, __ATOMIC_RELAXED, __HIP_MEMORY_SCOPE_AGENT) < target
                   && guard < (1 << 22)) {
                __builtin_amdgcn_s_sleep(2);
                ++guard;
            }
        }
        __syncthreads();

        // read full group h (4 b x 512) -> LDS (linear layout) for next step
        {
            const int hb2 = tid >> 7;       // 0..3
            const int k4  = tid & 127;      // u64 index within batch row
            const unsigned long long hv8 = __hip_atomic_load(
                (const unsigned long long*)hx
                    + ((((par * 2 + d) * 8 + bg) * 4 + hb2) << 7) + k4,
                __ATOMIC_RELAXED, __HIP_MEMORY_SCOPE_AGENT);
            *(unsigned long long*)&h_lds[hb2][k4 * 4] = hv8;
        }
        __syncthreads();
    }
}

// ---------------- launch ----------------
extern "C" void kernel_launch(void* const* d_in, const int* in_sizes, int n_in,
                              void* d_out, int out_size, void* d_ws, size_t ws_size,
                              hipStream_t stream) {
    const float* x      = (const float*)d_in[0];
    const float* wih_f0 = (const float*)d_in[1];
    const float* bih_f0 = (const float*)d_in[2];
    const float* whh_f0 = (const float*)d_in[3];
    const float* wih_b0 = (const float*)d_in[4];
    const float* bih_b0 = (const float*)d_in[5];
    const float* whh_b0 = (const float*)d_in[6];
    const float* wih_f1 = (const float*)d_in[7];
    const float* bih_f1 = (const float*)d_in[8];
    const float* whh_f1 = (const float*)d_in[9];
    const float* wih_b1 = (const float*)d_in[10];
    const float* bih_b1 = (const float*)d_in[11];
    const float* whh_b1 = (const float*)d_in[12];

    char* ws = (char*)d_ws;
    f16*   xh   = (f16*)(ws);                       // 16 MB (dead after gemm L0)
    uint*  hx   = (uint*)(ws);                      // 128 KB, reuses dead xh region
    unsigned* cnt = (unsigned*)(ws + 131072);       // 64 B, also inside xh region
    f16*   wih0 = (f16*)(ws + 16777216);            // 4 MB
    f16*   wih1 = (f16*)(ws + 20971520);            // 8 MB
    uint*  wr0  = (uint*)(ws + 29360128);           // 4 MB
    uint*  wr1  = (uint*)(ws + 33554432);           // 4 MB
    f16*   xp   = (f16*)(ws + 37748736);            // 128 MB
    f16*   interh = (f16*)d_out;                    // inter-layer buffer inside d_out

    auto cast = [&](const float* in, f16* o, int n) {
        int n4 = n / 4;
        cast_f32_f16<<<(n4 + 255) / 256, 256, 0, stream>>>(in, o, n4);
    };
    cast(x, xh, 8388608);
    cast(wih_f0, wih0, 1048576);
    cast(wih_b0, wih0 + 1048576, 1048576);
    cast(wih_f1, wih1, 2097152);
    cast(wih_b1, wih1 + 2097152, 2097152);
    pack_whh_reg<<<4096, 256, 0, stream>>>(whh_f0, whh_b0, wr0);
    pack_whh_reg<<<4096, 256, 0, stream>>>(whh_f1, whh_b1, wr1);

    // layer 0
    gemm_proj<<<dim3(128, 32), 256, 0, stream>>>(xh, wih0, bih_f0, bih_b0, xp, 512);
    hipMemsetAsync(cnt, 0, 64, stream);
    lstm_rec<f16><<<256, 512, 0, stream>>>(xp, wr0, hx, cnt, interh);
    // layer 1
    gemm_proj<<<dim3(128, 32), 256, 0, stream>>>(interh, wih1, bih_f1, bih_b1, xp, 1024);
    hipMemsetAsync(cnt, 0, 64, stream);
    lstm_rec<float><<<256, 512, 0, stream>>>(xp, wr1, hx, cnt, (float*)d_out);
}